// Round 2
// baseline (1662.213 us; speedup 1.0000x reference)
//
#include <hip/hip_runtime.h>
#include <cstdint>

#define DIVUP(a,b) (((a)+(b)-1)/(b))

__device__ __forceinline__ float cubicw(float x) {
  // PyTorch bicubic kernel, a = -0.75
  float ax = fabsf(x);
  float ax2 = ax * ax;
  float ax3 = ax2 * ax;
  if (ax <= 1.0f) return 1.25f * ax3 - 2.25f * ax2 + 1.0f;
  if (ax < 2.0f)  return -0.75f * ax3 + 3.75f * ax2 - 6.0f * ax + 3.0f;
  return 0.0f;
}

// S[b,pix] = sum_c x[b,c,pix]^2
__global__ void sumsq_kernel(const float* __restrict__ x, float* __restrict__ S,
                             int C, int HW, int total) {
  int i = blockIdx.x * blockDim.x + threadIdx.x;
  if (i >= total) return;
  int pix = i % HW, b = i / HW;
  const float* p = x + (size_t)b * C * HW + pix;
  float s = 0.f;
  for (int c = 0; c < C; ++c) { float v = p[(size_t)c * HW]; s += v * v; }
  S[i] = s;
}

// invn[b,p] = 1 / max(sqrt(3x3 zero-padded window sum of S), 1e-12)
__global__ void invnorm_kernel(const float* __restrict__ S, float* __restrict__ invn,
                               int H, int W, int total) {
  int i = blockIdx.x * blockDim.x + threadIdx.x;
  if (i >= total) return;
  int p = i % (H * W), b = i / (H * W);
  int ph = p / W, pw = p % W;
  const float* Sb = S + (size_t)b * H * W;
  float s = 0.f;
  for (int ki = 0; ki < 3; ++ki) {
    int y = ph + ki - 1;
    if (y < 0 || y >= H) continue;
    for (int kj = 0; kj < 3; ++kj) {
      int xx = pw + kj - 1;
      if (xx < 0 || xx >= W) continue;
      s += Sb[y * W + xx];
    }
  }
  float n = fmaxf(sqrtf(s), 1e-12f);
  invn[i] = 1.0f / n;
}

// l-layout descriptors: out[b][d][p] = unfold(x)[d,p] * invn[b,p]   (D-major)
__global__ void desc_l_kernel(const float* __restrict__ x, const float* __restrict__ invn,
                              float* __restrict__ out, int C, int H, int W, int total) {
  int i = blockIdx.x * blockDim.x + threadIdx.x;
  if (i >= total) return;
  int HW = H * W, D = C * 9;
  int p = i % HW;
  int d = (i / HW) % D;
  int b = i / (HW * D);
  int c = d / 9, r = d % 9, ki = r / 3, kj = r % 3;
  int ph = p / W, pw = p % W;
  int y = ph + ki - 1, xx = pw + kj - 1;
  float v = 0.f;
  if (y >= 0 && y < H && xx >= 0 && xx < W) v = x[((size_t)(b * C + c) * H + y) * W + xx];
  out[i] = v * invn[b * HW + p];
}

// r-layout descriptors: out[b][p][d]  (N-major rows of length D)
__global__ void desc_r_kernel(const float* __restrict__ x, const float* __restrict__ invn,
                              float* __restrict__ out, int C, int H, int W, int total) {
  int i = blockIdx.x * blockDim.x + threadIdx.x;
  if (i >= total) return;
  int HW = H * W, D = C * 9;
  int d = i % D;
  int p = (i / D) % HW;
  int b = i / (D * HW);
  int c = d / 9, r = d % 9, ki = r / 3, kj = r % 3;
  int ph = p / W, pw = p % W;
  int y = ph + ki - 1, xx = pw + kj - 1;
  float v = 0.f;
  if (y >= 0 && y < H && xx >= 0 && xx < W) v = x[((size_t)(b * C + c) * H + y) * W + xx];
  out[i] = v * invn[b * HW + p];
}

// Axis-1 bicubic upsample to 4096 rows: out[b][n][j] = sum_t w[t]*Rin[b][clip(idx)][j]
__global__ void upsample_n_kernel(const float* __restrict__ Rin, float* __restrict__ out,
                                  int Nin, int cols, float invscale, int total) {
  int i = blockIdx.x * blockDim.x + threadIdx.x;
  if (i >= total) return;
  int j = i % cols;
  int n = (i / cols) & 4095;
  int b = i / (cols * 4096);
  float src = (n + 0.5f) * invscale - 0.5f;
  float f = floorf(src);
  float tt = src - f;
  int fi = (int)f;
  const float* Rb = Rin + (size_t)b * Nin * cols;
  float s = 0.f;
#pragma unroll
  for (int tp = 0; tp < 4; ++tp) {
    int ii = min(max(fi + tp - 1, 0), Nin - 1);
    s += cubicw(tt - (float)(tp - 1)) * Rb[(size_t)ii * cols + j];
  }
  out[i] = s;
}

__global__ void init_packed_kernel(unsigned long long* __restrict__ p, int n) {
  int i = blockIdx.x * blockDim.x + threadIdx.x;
  if (i < n) p[i] = 0ull;
}

// 64x64-tile fp32 GEMM (4x4 microtile) for the small correlations R2/R1.
__global__ __launch_bounds__(256)
void gemm64_kernel(const float* __restrict__ A, const float* __restrict__ B,
                   float* __restrict__ C, int M, int N, int K) {
  int b = blockIdx.z;
  const float* Ab = A + (size_t)b * M * K;
  const float* Bb = B + (size_t)b * K * N;
  __shared__ float As[16][68];
  __shared__ float Bs[16][64];
  int row0 = blockIdx.y * 64;
  int col0 = blockIdx.x * 64;
  int t = threadIdx.x;
  int tx = t & 15, ty = t >> 4;
  float acc[4][4] = {};
  int la_r = t >> 2;
  int la_k = (t & 3) << 2;
  int lb_r = t >> 4;
  int lb_c = (t & 15) << 2;
  const float* Aptr = Ab + (size_t)(row0 + la_r) * K + la_k;
  const float* Bptr = Bb + (size_t)lb_r * N + col0 + lb_c;
  for (int k0 = 0; k0 < K; k0 += 16) {
    float4 av = *(const float4*)(Aptr + k0);
    float4 bv = *(const float4*)(Bptr + (size_t)k0 * N);
    __syncthreads();
    As[la_k + 0][la_r] = av.x;
    As[la_k + 1][la_r] = av.y;
    As[la_k + 2][la_r] = av.z;
    As[la_k + 3][la_r] = av.w;
    *(float4*)&Bs[lb_r][lb_c] = bv;
    __syncthreads();
#pragma unroll
    for (int k = 0; k < 16; ++k) {
      float4 a = *(const float4*)&As[k][ty << 2];
      float4 bq = *(const float4*)&Bs[k][tx << 2];
      float av4[4] = {a.x, a.y, a.z, a.w};
      float bv4[4] = {bq.x, bq.y, bq.z, bq.w};
#pragma unroll
      for (int ii = 0; ii < 4; ++ii)
#pragma unroll
        for (int jj = 0; jj < 4; ++jj)
          acc[ii][jj] = fmaf(av4[ii], bv4[jj], acc[ii][jj]);
    }
  }
  float* Cb = C + (size_t)b * M * N;
#pragma unroll
  for (int ii = 0; ii < 4; ++ii) {
    float4 v = make_float4(acc[ii][0], acc[ii][1], acc[ii][2], acc[ii][3]);
    *(float4*)&Cb[(size_t)(row0 + (ty << 2) + ii) * N + col0 + (tx << 2)] = v;
  }
}

// 128x128-tile fp32 GEMM (8x8 microtile) fused with bicubic-tap add, /3,
// and packed max/argmax over rows (the ref axis). M=N=4096, K=576.
__global__ __launch_bounds__(256)
void gemm128_fused_kernel(const float* __restrict__ A, const float* __restrict__ Bm,
                          int M, int N, int K,
                          const float* __restrict__ up2, const float* __restrict__ up1,
                          unsigned long long* __restrict__ packed) {
  int b = blockIdx.z;
  const float* Ab = A + (size_t)b * M * K;
  const float* Bb = Bm + (size_t)b * K * N;
  __shared__ float smem[2 * 16 * 132];       // As[16][132] ++ Bs[16][132]
  float* As = smem;
  float* Bs = smem + 16 * 132;
  int row0 = blockIdx.y * 128;
  int col0 = blockIdx.x * 128;
  int t = threadIdx.x;
  int tx = t & 15, ty = t >> 4;
  float acc[8][8] = {};

  int ar = t & 127;                 // A row within tile (wave-contiguous)
  int akc = (t >> 7) * 8;           // k-chunk 0 or 8 (wave-uniform)
  int bk = t >> 4;                  // B k-row 0..15
  int bc = (t & 15) * 8;            // B col chunk
  const float* Aptr = Ab + (size_t)(row0 + ar) * K + akc;
  const float* Bptr = Bb + (size_t)bk * N + col0 + bc;

  for (int k0 = 0; k0 < K; k0 += 16) {
    float4 a0 = *(const float4*)(Aptr + k0);
    float4 a1 = *(const float4*)(Aptr + k0 + 4);
    float4 b0 = *(const float4*)(Bptr + (size_t)k0 * N);
    float4 b1 = *(const float4*)(Bptr + (size_t)k0 * N + 4);
    __syncthreads();
    As[(akc + 0) * 132 + ar] = a0.x;
    As[(akc + 1) * 132 + ar] = a0.y;
    As[(akc + 2) * 132 + ar] = a0.z;
    As[(akc + 3) * 132 + ar] = a0.w;
    As[(akc + 4) * 132 + ar] = a1.x;
    As[(akc + 5) * 132 + ar] = a1.y;
    As[(akc + 6) * 132 + ar] = a1.z;
    As[(akc + 7) * 132 + ar] = a1.w;
    *(float4*)&Bs[bk * 132 + bc] = b0;
    *(float4*)&Bs[bk * 132 + bc + 4] = b1;
    __syncthreads();
#pragma unroll
    for (int k = 0; k < 16; ++k) {
      float4 af0 = *(const float4*)&As[k * 132 + (ty << 2)];
      float4 af1 = *(const float4*)&As[k * 132 + (ty << 2) + 64];
      float4 bf0 = *(const float4*)&Bs[k * 132 + (tx << 2)];
      float4 bf1 = *(const float4*)&Bs[k * 132 + (tx << 2) + 64];
      float av[8] = {af0.x, af0.y, af0.z, af0.w, af1.x, af1.y, af1.z, af1.w};
      float bv[8] = {bf0.x, bf0.y, bf0.z, bf0.w, bf1.x, bf1.y, bf1.z, bf1.w};
#pragma unroll
      for (int ii = 0; ii < 8; ++ii)
#pragma unroll
        for (int jj = 0; jj < 8; ++jj)
          acc[ii][jj] = fmaf(av[ii], bv[jj], acc[ii][jj]);
    }
  }

  // ---- fused epilogue: bicubic taps + /3 + packed max/argmax over rows ----
  __syncthreads();                           // done reading As/Bs; overlay red
  unsigned long long* red = (unsigned long long*)smem;  // [16][128]

#pragma unroll
  for (int jj = 0; jj < 8; ++jj) {
    int cl = (tx << 2) + (jj & 3) + ((jj >> 2) << 6);
    int gm = col0 + cl;
    float src2 = (gm + 0.5f) * 0.25f - 0.5f;
    float f2 = floorf(src2); float t2 = src2 - f2; int i2 = (int)f2;
    int idx2[4]; float w2[4];
#pragma unroll
    for (int tp = 0; tp < 4; ++tp) {
      idx2[tp] = min(max(i2 + tp - 1, 0), 1023);
      w2[tp] = cubicw(t2 - (float)(tp - 1));
    }
    float src1 = (gm + 0.5f) * 0.0625f - 0.5f;
    float f1 = floorf(src1); float t1 = src1 - f1; int i1 = (int)f1;
    int idx1[4]; float w1[4];
#pragma unroll
    for (int tp = 0; tp < 4; ++tp) {
      idx1[tp] = min(max(i1 + tp - 1, 0), 255);
      w1[tp] = cubicw(t1 - (float)(tp - 1));
    }
    unsigned long long best = 0ull;
#pragma unroll
    for (int ii = 0; ii < 8; ++ii) {
      int gn = row0 + (ty << 2) + (ii & 3) + ((ii >> 2) << 6);
      const float* r2row = up2 + ((size_t)b * 4096 + gn) * 1024;
      const float* r1row = up1 + ((size_t)b * 4096 + gn) * 256;
      float v = acc[ii][jj];
      v += w2[0] * r2row[idx2[0]] + w2[1] * r2row[idx2[1]]
         + w2[2] * r2row[idx2[2]] + w2[3] * r2row[idx2[3]];
      v += w1[0] * r1row[idx1[0]] + w1[1] * r1row[idx1[1]]
         + w1[2] * r1row[idx1[2]] + w1[3] * r1row[idx1[3]];
      v *= (1.0f / 3.0f);
      unsigned int fb = __float_as_uint(v);
      unsigned int key = (fb & 0x80000000u) ? ~fb : (fb | 0x80000000u);
      unsigned long long pk = ((unsigned long long)key << 32)
                            | (unsigned long long)(0xFFFFFFFFu - (unsigned)gn);
      best = best > pk ? best : pk;
    }
    red[ty * 128 + cl] = best;
  }
  __syncthreads();
  if (t < 128) {
    unsigned long long bb = red[t];
#pragma unroll
    for (int r = 1; r < 16; ++r) {
      unsigned long long v = red[r * 128 + t];
      bb = bb > v ? bb : v;
    }
    atomicMax(&packed[(size_t)b * 4096 + col0 + t], bb);
  }
}

__global__ void finalize_kernel(const unsigned long long* __restrict__ packed,
                                float* __restrict__ s3_out, int* __restrict__ arg, int total) {
  int i = blockIdx.x * blockDim.x + threadIdx.x;
  if (i >= total) return;
  unsigned long long pk = packed[i];
  unsigned int key = (unsigned int)(pk >> 32);
  unsigned int fb = (key & 0x80000000u) ? (key ^ 0x80000000u) : ~key;
  s3_out[i] = __uint_as_float(fb);
  arg[i] = (int)(0xFFFFFFFFu - (unsigned int)(pk & 0xFFFFFFFFull));
}

// fold(gather(unfold(ref, KK,PP,SS), arg)) / 9 — pure gather, <=9 taps/output.
template<int KK, int SS, int PP>
__global__ void fold_gather_kernel(const float* __restrict__ ref, const int* __restrict__ arg,
                                   float* __restrict__ out, int C, int H, int W, int total) {
  int i = blockIdx.x * blockDim.x + threadIdx.x;
  if (i >= total) return;
  int w = i % W;
  int h = (i / W) % H;
  int c = (i / (W * H)) % C;
  int b = i / (W * H * C);
  int y = h + PP, x = w + PP;
  int ho_lo = (y - KK + 1) > 0 ? (y - KK + 1 + SS - 1) / SS : 0;
  int ho_hi = min(63, y / SS);
  int wo_lo = (x - KK + 1) > 0 ? (x - KK + 1 + SS - 1) / SS : 0;
  int wo_hi = min(63, x / SS);
  const int* argb = arg + b * 4096;
  const float* refb = ref + (size_t)(b * C + c) * H * W;
  float acc = 0.f;
  for (int ho = ho_lo; ho <= ho_hi; ++ho) {
    int ki = y - SS * ho;
    for (int wo = wo_lo; wo <= wo_hi; ++wo) {
      int kj = x - SS * wo;
      int q = argb[(ho << 6) + wo];
      int qh = q >> 6, qw = q & 63;
      int ry = SS * qh + ki - PP;
      int rx = SS * qw + kj - PP;
      if (ry >= 0 && ry < H && rx >= 0 && rx < W) acc += refb[ry * W + rx];
    }
  }
  out[i] = acc * (1.0f / 9.0f);
}

extern "C" void kernel_launch(void* const* d_in, const int* in_sizes, int n_in,
                              void* d_out, int out_size, void* d_ws, size_t ws_size,
                              hipStream_t stream) {
  const float* lrsr1 = (const float*)d_in[0];
  const float* lrsr2 = (const float*)d_in[1];
  const float* lrsr3 = (const float*)d_in[2];
  const float* refsr1 = (const float*)d_in[3];
  const float* refsr2 = (const float*)d_in[4];
  const float* refsr3 = (const float*)d_in[5];
  const float* ref1 = (const float*)d_in[6];
  const float* ref2 = (const float*)d_in[7];
  const float* ref3 = (const float*)d_in[8];
  float* out = (float*)d_out;
  float* ws = (float*)d_ws;

  const int B = 2;
  size_t off_r3n = 0;                                   // [2,4096,576]
  size_t off_l3n = off_r3n + (size_t)B * 4096 * 576;    // [2,576,4096]
  size_t off_r2n = off_l3n + (size_t)B * 576 * 4096;    // [2,1024,1152]
  size_t off_l2n = off_r2n + (size_t)B * 1024 * 1152;   // [2,1152,1024]
  size_t off_r1n = off_l2n + (size_t)B * 1152 * 1024;   // [2,256,2304]
  size_t off_l1n = off_r1n + (size_t)B * 256 * 2304;    // [2,2304,256]
  size_t off_R2  = off_l1n + (size_t)B * 2304 * 256;    // [2,1024,1024]
  size_t off_R1  = off_R2  + (size_t)B * 1024 * 1024;   // [2,256,256]
  size_t off_up2 = off_R1  + (size_t)B * 256 * 256;     // [2,4096,1024]
  size_t off_up1 = off_up2 + (size_t)B * 4096 * 1024;   // [2,4096,256]
  size_t off_S   = off_up1 + (size_t)B * 4096 * 256;    // [2,4096]
  size_t off_invn= off_S   + (size_t)B * 4096;          // [2,4096]
  size_t off_pk  = off_invn+ (size_t)B * 4096;          // [2,4096] u64
  size_t off_arg = off_pk  + (size_t)B * 4096 * 2;      // [2,4096] int

  auto run_desc = [&](const float* x, int C, int H, int W, float* outbuf, bool r_layout) {
    int HW = H * W;
    int tS = B * HW;
    sumsq_kernel<<<DIVUP(tS, 256), 256, 0, stream>>>(x, ws + off_S, C, HW, tS);
    invnorm_kernel<<<DIVUP(tS, 256), 256, 0, stream>>>(ws + off_S, ws + off_invn, H, W, tS);
    int tD = B * C * 9 * HW;
    if (r_layout)
      desc_r_kernel<<<DIVUP(tD, 256), 256, 0, stream>>>(x, ws + off_invn, outbuf, C, H, W, tD);
    else
      desc_l_kernel<<<DIVUP(tD, 256), 256, 0, stream>>>(x, ws + off_invn, outbuf, C, H, W, tD);
  };

  run_desc(lrsr3, 64, 64, 64, ws + off_l3n, false);
  run_desc(refsr3, 64, 64, 64, ws + off_r3n, true);
  run_desc(lrsr2, 128, 32, 32, ws + off_l2n, false);
  run_desc(refsr2, 128, 32, 32, ws + off_r2n, true);
  run_desc(lrsr1, 256, 16, 16, ws + off_l1n, false);
  run_desc(refsr1, 256, 16, 16, ws + off_r1n, true);

  // small correlation GEMMs R2, R1
  {
    dim3 g(1024 / 64, 1024 / 64, B);
    gemm64_kernel<<<g, 256, 0, stream>>>(ws + off_r2n, ws + off_l2n, ws + off_R2,
                                         1024, 1024, 1152);
  }
  {
    dim3 g(256 / 64, 256 / 64, B);
    gemm64_kernel<<<g, 256, 0, stream>>>(ws + off_r1n, ws + off_l1n, ws + off_R1,
                                         256, 256, 2304);
  }

  // axis-1 bicubic upsample of R2 (x4) and R1 (x16) to 4096 rows
  {
    int tU2 = B * 4096 * 1024;
    upsample_n_kernel<<<DIVUP(tU2, 256), 256, 0, stream>>>(ws + off_R2, ws + off_up2,
                                                           1024, 1024, 0.25f, tU2);
    int tU1 = B * 4096 * 256;
    upsample_n_kernel<<<DIVUP(tU1, 256), 256, 0, stream>>>(ws + off_R1, ws + off_up1,
                                                           256, 256, 0.0625f, tU1);
  }

  unsigned long long* pk = (unsigned long long*)(ws + off_pk);
  init_packed_kernel<<<DIVUP(B * 4096, 256), 256, 0, stream>>>(pk, B * 4096);

  // fused R3 GEMM + bicubic add + max/argmax  (128x128 tiles, 8x8 microtile)
  {
    dim3 g(4096 / 128, 4096 / 128, B);
    gemm128_fused_kernel<<<g, 256, 0, stream>>>(ws + off_r3n, ws + off_l3n,
                                                4096, 4096, 576,
                                                ws + off_up2, ws + off_up1, pk);
  }

  int* argp = (int*)(ws + off_arg);
  finalize_kernel<<<DIVUP(B * 4096, 256), 256, 0, stream>>>(pk, out, argp, B * 4096);

  // transfer: fold(gather(unfold(ref_lvX)))/9
  float* T3 = out + 8192;
  float* T2 = T3 + (size_t)B * 256 * 64 * 64;
  float* T1 = T2 + (size_t)B * 128 * 128 * 128;
  {
    int tt = B * 256 * 64 * 64;
    fold_gather_kernel<3, 1, 1><<<DIVUP(tt, 256), 256, 0, stream>>>(ref3, argp, T3, 256, 64, 64, tt);
  }
  {
    int tt = B * 128 * 128 * 128;
    fold_gather_kernel<6, 2, 2><<<DIVUP(tt, 256), 256, 0, stream>>>(ref2, argp, T2, 128, 128, 128, tt);
  }
  {
    int tt = B * 64 * 256 * 256;
    fold_gather_kernel<12, 4, 4><<<DIVUP(tt, 256), 256, 0, stream>>>(ref1, argp, T1, 64, 256, 256, tt);
  }
}

// Round 3
// 1474.121 us; speedup vs baseline: 1.1276x; 1.1276x over previous
//
#include <hip/hip_runtime.h>
#include <cstdint>

#define DIVUP(a,b) (((a)+(b)-1)/(b))

__device__ __forceinline__ float cubicw(float x) {
  // PyTorch bicubic kernel, a = -0.75
  float ax = fabsf(x);
  float ax2 = ax * ax;
  float ax3 = ax2 * ax;
  if (ax <= 1.0f) return 1.25f * ax3 - 2.25f * ax2 + 1.0f;
  if (ax < 2.0f)  return -0.75f * ax3 + 3.75f * ax2 - 6.0f * ax + 3.0f;
  return 0.0f;
}

// S[b,pix] = sum_c x[b,c,pix]^2
__global__ void sumsq_kernel(const float* __restrict__ x, float* __restrict__ S,
                             int C, int HW, int total) {
  int i = blockIdx.x * blockDim.x + threadIdx.x;
  if (i >= total) return;
  int pix = i % HW, b = i / HW;
  const float* p = x + (size_t)b * C * HW + pix;
  float s = 0.f;
  for (int c = 0; c < C; ++c) { float v = p[(size_t)c * HW]; s += v * v; }
  S[i] = s;
}

// invn[b,p] = 1 / max(sqrt(3x3 zero-padded window sum of S), 1e-12)
__global__ void invnorm_kernel(const float* __restrict__ S, float* __restrict__ invn,
                               int H, int W, int total) {
  int i = blockIdx.x * blockDim.x + threadIdx.x;
  if (i >= total) return;
  int p = i % (H * W), b = i / (H * W);
  int ph = p / W, pw = p % W;
  const float* Sb = S + (size_t)b * H * W;
  float s = 0.f;
  for (int ki = 0; ki < 3; ++ki) {
    int y = ph + ki - 1;
    if (y < 0 || y >= H) continue;
    for (int kj = 0; kj < 3; ++kj) {
      int xx = pw + kj - 1;
      if (xx < 0 || xx >= W) continue;
      s += Sb[y * W + xx];
    }
  }
  float n = fmaxf(sqrtf(s), 1e-12f);
  invn[i] = 1.0f / n;
}

// l-layout descriptors: out[b][d][p] = unfold(x)[d,p] * invn[b,p]   (D-major)
__global__ void desc_l_kernel(const float* __restrict__ x, const float* __restrict__ invn,
                              float* __restrict__ out, int C, int H, int W, int total) {
  int i = blockIdx.x * blockDim.x + threadIdx.x;
  if (i >= total) return;
  int HW = H * W, D = C * 9;
  int p = i % HW;
  int d = (i / HW) % D;
  int b = i / (HW * D);
  int c = d / 9, r = d % 9, ki = r / 3, kj = r % 3;
  int ph = p / W, pw = p % W;
  int y = ph + ki - 1, xx = pw + kj - 1;
  float v = 0.f;
  if (y >= 0 && y < H && xx >= 0 && xx < W) v = x[((size_t)(b * C + c) * H + y) * W + xx];
  out[i] = v * invn[b * HW + p];
}

// r-layout descriptors: out[b][p][d]  (N-major rows of length D)
__global__ void desc_r_kernel(const float* __restrict__ x, const float* __restrict__ invn,
                              float* __restrict__ out, int C, int H, int W, int total) {
  int i = blockIdx.x * blockDim.x + threadIdx.x;
  if (i >= total) return;
  int HW = H * W, D = C * 9;
  int d = i % D;
  int p = (i / D) % HW;
  int b = i / (D * HW);
  int c = d / 9, r = d % 9, ki = r / 3, kj = r % 3;
  int ph = p / W, pw = p % W;
  int y = ph + ki - 1, xx = pw + kj - 1;
  float v = 0.f;
  if (y >= 0 && y < H && xx >= 0 && xx < W) v = x[((size_t)(b * C + c) * H + y) * W + xx];
  out[i] = v * invn[b * HW + p];
}

// Axis-1 bicubic upsample to 4096 rows: out[b][n][j] = sum_t w[t]*Rin[b][clip(idx)][j]
__global__ void upsample_n_kernel(const float* __restrict__ Rin, float* __restrict__ out,
                                  int Nin, int cols, float invscale, int total) {
  int i = blockIdx.x * blockDim.x + threadIdx.x;
  if (i >= total) return;
  int j = i % cols;
  int n = (i / cols) & 4095;
  int b = i / (cols * 4096);
  float src = (n + 0.5f) * invscale - 0.5f;
  float f = floorf(src);
  float tt = src - f;
  int fi = (int)f;
  const float* Rb = Rin + (size_t)b * Nin * cols;
  float s = 0.f;
#pragma unroll
  for (int tp = 0; tp < 4; ++tp) {
    int ii = min(max(fi + tp - 1, 0), Nin - 1);
    s += cubicw(tt - (float)(tp - 1)) * Rb[(size_t)ii * cols + j];
  }
  out[i] = s;
}

__global__ void init_packed_kernel(unsigned long long* __restrict__ p, int n) {
  int i = blockIdx.x * blockDim.x + threadIdx.x;
  if (i < n) p[i] = 0ull;
}

// 64x64-tile fp32 GEMM (4x4 microtile), register-prefetch pipelined.
__global__ __launch_bounds__(256)
void gemm64_kernel(const float* __restrict__ A, const float* __restrict__ B,
                   float* __restrict__ C, int M, int N, int K) {
  int b = blockIdx.z;
  const float* Ab = A + (size_t)b * M * K;
  const float* Bb = B + (size_t)b * K * N;
  __shared__ float As[16][68];
  __shared__ float Bs[16][64];
  int row0 = blockIdx.y * 64;
  int col0 = blockIdx.x * 64;
  int t = threadIdx.x;
  int tx = t & 15, ty = t >> 4;
  float acc[4][4] = {};
  int la_r = t >> 2;
  int la_k = (t & 3) << 2;
  int lb_r = t >> 4;
  int lb_c = (t & 15) << 2;
  const float* Aptr = Ab + (size_t)(row0 + la_r) * K + la_k;
  const float* Bptr = Bb + (size_t)lb_r * N + col0 + lb_c;
  float4 av = *(const float4*)(Aptr);
  float4 bv = *(const float4*)(Bptr);
  for (int k0 = 0; k0 < K; k0 += 16) {
    __syncthreads();
    As[la_k + 0][la_r] = av.x;
    As[la_k + 1][la_r] = av.y;
    As[la_k + 2][la_r] = av.z;
    As[la_k + 3][la_r] = av.w;
    *(float4*)&Bs[lb_r][lb_c] = bv;
    __syncthreads();
    if (k0 + 16 < K) {                     // prefetch next k-tile into regs
      av = *(const float4*)(Aptr + k0 + 16);
      bv = *(const float4*)(Bptr + (size_t)(k0 + 16) * N);
    }
#pragma unroll
    for (int k = 0; k < 16; ++k) {
      float4 a = *(const float4*)&As[k][ty << 2];
      float4 bq = *(const float4*)&Bs[k][tx << 2];
      float av4[4] = {a.x, a.y, a.z, a.w};
      float bv4[4] = {bq.x, bq.y, bq.z, bq.w};
#pragma unroll
      for (int ii = 0; ii < 4; ++ii)
#pragma unroll
        for (int jj = 0; jj < 4; ++jj)
          acc[ii][jj] = fmaf(av4[ii], bv4[jj], acc[ii][jj]);
    }
  }
  float* Cb = C + (size_t)b * M * N;
#pragma unroll
  for (int ii = 0; ii < 4; ++ii) {
    float4 v = make_float4(acc[ii][0], acc[ii][1], acc[ii][2], acc[ii][3]);
    *(float4*)&Cb[(size_t)(row0 + (ty << 2) + ii) * N + col0 + (tx << 2)] = v;
  }
}

// 128x128-tile fp32 GEMM (8x8 microtile), register-prefetch pipelined, fused
// with bicubic-tap add, /3, packed max/argmax over rows. M=N=4096, K=576.
__global__ __launch_bounds__(256)
void gemm128_fused_kernel(const float* __restrict__ A, const float* __restrict__ Bm,
                          int M, int N, int K,
                          const float* __restrict__ up2, const float* __restrict__ up1,
                          unsigned long long* __restrict__ packed) {
  int b = blockIdx.z;
  const float* Ab = A + (size_t)b * M * K;
  const float* Bb = Bm + (size_t)b * K * N;
  __shared__ float smem[2 * 16 * 132];       // As[16][132] ++ Bs[16][132]
  float* As = smem;
  float* Bs = smem + 16 * 132;
  int row0 = blockIdx.y * 128;
  int col0 = blockIdx.x * 128;
  int t = threadIdx.x;
  int tx = t & 15, ty = t >> 4;
  float acc[8][8] = {};

  int ar = t & 127;                 // A row within tile
  int akc = (t >> 7) * 8;           // k-chunk 0 or 8 (wave-uniform)
  int bk = t >> 4;                  // B k-row 0..15
  int bc = (t & 15) * 8;            // B col chunk
  const float* Aptr = Ab + (size_t)(row0 + ar) * K + akc;
  const float* Bptr = Bb + (size_t)bk * N + col0 + bc;

  float4 a0 = *(const float4*)(Aptr);
  float4 a1 = *(const float4*)(Aptr + 4);
  float4 b0 = *(const float4*)(Bptr);
  float4 b1 = *(const float4*)(Bptr + 4);

  for (int k0 = 0; k0 < K; k0 += 16) {
    __syncthreads();
    As[(akc + 0) * 132 + ar] = a0.x;
    As[(akc + 1) * 132 + ar] = a0.y;
    As[(akc + 2) * 132 + ar] = a0.z;
    As[(akc + 3) * 132 + ar] = a0.w;
    As[(akc + 4) * 132 + ar] = a1.x;
    As[(akc + 5) * 132 + ar] = a1.y;
    As[(akc + 6) * 132 + ar] = a1.z;
    As[(akc + 7) * 132 + ar] = a1.w;
    *(float4*)&Bs[bk * 132 + bc] = b0;
    *(float4*)&Bs[bk * 132 + bc + 4] = b1;
    __syncthreads();
    if (k0 + 16 < K) {                     // prefetch next k-tile into regs;
      a0 = *(const float4*)(Aptr + k0 + 16);           // latency hides under
      a1 = *(const float4*)(Aptr + k0 + 20);           // the 16-step compute
      b0 = *(const float4*)(Bptr + (size_t)(k0 + 16) * N);
      b1 = *(const float4*)(Bptr + (size_t)(k0 + 16) * N + 4);
    }
#pragma unroll
    for (int k = 0; k < 16; ++k) {
      float4 af0 = *(const float4*)&As[k * 132 + (ty << 2)];
      float4 af1 = *(const float4*)&As[k * 132 + (ty << 2) + 64];
      float4 bf0 = *(const float4*)&Bs[k * 132 + (tx << 2)];
      float4 bf1 = *(const float4*)&Bs[k * 132 + (tx << 2) + 64];
      float av[8] = {af0.x, af0.y, af0.z, af0.w, af1.x, af1.y, af1.z, af1.w};
      float bv[8] = {bf0.x, bf0.y, bf0.z, bf0.w, bf1.x, bf1.y, bf1.z, bf1.w};
#pragma unroll
      for (int ii = 0; ii < 8; ++ii)
#pragma unroll
        for (int jj = 0; jj < 8; ++jj)
          acc[ii][jj] = fmaf(av[ii], bv[jj], acc[ii][jj]);
    }
  }

  // ---- fused epilogue: bicubic taps + /3 + packed max/argmax over rows ----
  __syncthreads();                           // done reading As/Bs; overlay red
  unsigned long long* red = (unsigned long long*)smem;  // [16][128]

#pragma unroll
  for (int jj = 0; jj < 8; ++jj) {
    int cl = (tx << 2) + (jj & 3) + ((jj >> 2) << 6);
    int gm = col0 + cl;
    float src2 = (gm + 0.5f) * 0.25f - 0.5f;
    float f2 = floorf(src2); float t2 = src2 - f2; int i2 = (int)f2;
    int idx2[4]; float w2[4];
#pragma unroll
    for (int tp = 0; tp < 4; ++tp) {
      idx2[tp] = min(max(i2 + tp - 1, 0), 1023);
      w2[tp] = cubicw(t2 - (float)(tp - 1));
    }
    float src1 = (gm + 0.5f) * 0.0625f - 0.5f;
    float f1 = floorf(src1); float t1 = src1 - f1; int i1 = (int)f1;
    int idx1[4]; float w1[4];
#pragma unroll
    for (int tp = 0; tp < 4; ++tp) {
      idx1[tp] = min(max(i1 + tp - 1, 0), 255);
      w1[tp] = cubicw(t1 - (float)(tp - 1));
    }
    unsigned long long best = 0ull;
#pragma unroll
    for (int ii = 0; ii < 8; ++ii) {
      int gn = row0 + (ty << 2) + (ii & 3) + ((ii >> 2) << 6);
      const float* r2row = up2 + ((size_t)b * 4096 + gn) * 1024;
      const float* r1row = up1 + ((size_t)b * 4096 + gn) * 256;
      float v = acc[ii][jj];
      v += w2[0] * r2row[idx2[0]] + w2[1] * r2row[idx2[1]]
         + w2[2] * r2row[idx2[2]] + w2[3] * r2row[idx2[3]];
      v += w1[0] * r1row[idx1[0]] + w1[1] * r1row[idx1[1]]
         + w1[2] * r1row[idx1[2]] + w1[3] * r1row[idx1[3]];
      v *= (1.0f / 3.0f);
      unsigned int fb = __float_as_uint(v);
      unsigned int key = (fb & 0x80000000u) ? ~fb : (fb | 0x80000000u);
      unsigned long long pk = ((unsigned long long)key << 32)
                            | (unsigned long long)(0xFFFFFFFFu - (unsigned)gn);
      best = best > pk ? best : pk;
    }
    red[ty * 128 + cl] = best;
  }
  __syncthreads();
  if (t < 128) {
    unsigned long long bb = red[t];
#pragma unroll
    for (int r = 1; r < 16; ++r) {
      unsigned long long v = red[r * 128 + t];
      bb = bb > v ? bb : v;
    }
    atomicMax(&packed[(size_t)b * 4096 + col0 + t], bb);
  }
}

__global__ void finalize_kernel(const unsigned long long* __restrict__ packed,
                                float* __restrict__ s3_out, int* __restrict__ arg, int total) {
  int i = blockIdx.x * blockDim.x + threadIdx.x;
  if (i >= total) return;
  unsigned long long pk = packed[i];
  unsigned int key = (unsigned int)(pk >> 32);
  unsigned int fb = (key & 0x80000000u) ? (key ^ 0x80000000u) : ~key;
  s3_out[i] = __uint_as_float(fb);
  arg[i] = (int)(0xFFFFFFFFu - (unsigned int)(pk & 0xFFFFFFFFull));
}

// fold(gather(unfold(ref, KK,PP,SS), arg)) / 9 — pure gather, <=9 taps/output.
template<int KK, int SS, int PP>
__global__ void fold_gather_kernel(const float* __restrict__ ref, const int* __restrict__ arg,
                                   float* __restrict__ out, int C, int H, int W, int total) {
  int i = blockIdx.x * blockDim.x + threadIdx.x;
  if (i >= total) return;
  int w = i % W;
  int h = (i / W) % H;
  int c = (i / (W * H)) % C;
  int b = i / (W * H * C);
  int y = h + PP, x = w + PP;
  int ho_lo = (y - KK + 1) > 0 ? (y - KK + 1 + SS - 1) / SS : 0;
  int ho_hi = min(63, y / SS);
  int wo_lo = (x - KK + 1) > 0 ? (x - KK + 1 + SS - 1) / SS : 0;
  int wo_hi = min(63, x / SS);
  const int* argb = arg + b * 4096;
  const float* refb = ref + (size_t)(b * C + c) * H * W;
  float acc = 0.f;
  for (int ho = ho_lo; ho <= ho_hi; ++ho) {
    int ki = y - SS * ho;
    for (int wo = wo_lo; wo <= wo_hi; ++wo) {
      int kj = x - SS * wo;
      int q = argb[(ho << 6) + wo];
      int qh = q >> 6, qw = q & 63;
      int ry = SS * qh + ki - PP;
      int rx = SS * qw + kj - PP;
      if (ry >= 0 && ry < H && rx >= 0 && rx < W) acc += refb[ry * W + rx];
    }
  }
  out[i] = acc * (1.0f / 9.0f);
}

extern "C" void kernel_launch(void* const* d_in, const int* in_sizes, int n_in,
                              void* d_out, int out_size, void* d_ws, size_t ws_size,
                              hipStream_t stream) {
  const float* lrsr1 = (const float*)d_in[0];
  const float* lrsr2 = (const float*)d_in[1];
  const float* lrsr3 = (const float*)d_in[2];
  const float* refsr1 = (const float*)d_in[3];
  const float* refsr2 = (const float*)d_in[4];
  const float* refsr3 = (const float*)d_in[5];
  const float* ref1 = (const float*)d_in[6];
  const float* ref2 = (const float*)d_in[7];
  const float* ref3 = (const float*)d_in[8];
  float* out = (float*)d_out;
  float* ws = (float*)d_ws;

  const int B = 2;
  size_t off_r3n = 0;                                   // [2,4096,576]
  size_t off_l3n = off_r3n + (size_t)B * 4096 * 576;    // [2,576,4096]
  size_t off_r2n = off_l3n + (size_t)B * 576 * 4096;    // [2,1024,1152]
  size_t off_l2n = off_r2n + (size_t)B * 1024 * 1152;   // [2,1152,1024]
  size_t off_r1n = off_l2n + (size_t)B * 1152 * 1024;   // [2,256,2304]
  size_t off_l1n = off_r1n + (size_t)B * 256 * 2304;    // [2,2304,256]
  size_t off_R2  = off_l1n + (size_t)B * 2304 * 256;    // [2,1024,1024]
  size_t off_R1  = off_R2  + (size_t)B * 1024 * 1024;   // [2,256,256]
  size_t off_up2 = off_R1  + (size_t)B * 256 * 256;     // [2,4096,1024]
  size_t off_up1 = off_up2 + (size_t)B * 4096 * 1024;   // [2,4096,256]
  size_t off_S   = off_up1 + (size_t)B * 4096 * 256;    // [2,4096]
  size_t off_invn= off_S   + (size_t)B * 4096;          // [2,4096]
  size_t off_pk  = off_invn+ (size_t)B * 4096;          // [2,4096] u64
  size_t off_arg = off_pk  + (size_t)B * 4096 * 2;      // [2,4096] int

  auto run_desc = [&](const float* x, int C, int H, int W, float* outbuf, bool r_layout) {
    int HW = H * W;
    int tS = B * HW;
    sumsq_kernel<<<DIVUP(tS, 256), 256, 0, stream>>>(x, ws + off_S, C, HW, tS);
    invnorm_kernel<<<DIVUP(tS, 256), 256, 0, stream>>>(ws + off_S, ws + off_invn, H, W, tS);
    int tD = B * C * 9 * HW;
    if (r_layout)
      desc_r_kernel<<<DIVUP(tD, 256), 256, 0, stream>>>(x, ws + off_invn, outbuf, C, H, W, tD);
    else
      desc_l_kernel<<<DIVUP(tD, 256), 256, 0, stream>>>(x, ws + off_invn, outbuf, C, H, W, tD);
  };

  run_desc(lrsr3, 64, 64, 64, ws + off_l3n, false);
  run_desc(refsr3, 64, 64, 64, ws + off_r3n, true);
  run_desc(lrsr2, 128, 32, 32, ws + off_l2n, false);
  run_desc(refsr2, 128, 32, 32, ws + off_r2n, true);
  run_desc(lrsr1, 256, 16, 16, ws + off_l1n, false);
  run_desc(refsr1, 256, 16, 16, ws + off_r1n, true);

  // small correlation GEMMs R2, R1
  {
    dim3 g(1024 / 64, 1024 / 64, B);
    gemm64_kernel<<<g, 256, 0, stream>>>(ws + off_r2n, ws + off_l2n, ws + off_R2,
                                         1024, 1024, 1152);
  }
  {
    dim3 g(256 / 64, 256 / 64, B);
    gemm64_kernel<<<g, 256, 0, stream>>>(ws + off_r1n, ws + off_l1n, ws + off_R1,
                                         256, 256, 2304);
  }

  // axis-1 bicubic upsample of R2 (x4) and R1 (x16) to 4096 rows
  {
    int tU2 = B * 4096 * 1024;
    upsample_n_kernel<<<DIVUP(tU2, 256), 256, 0, stream>>>(ws + off_R2, ws + off_up2,
                                                           1024, 1024, 0.25f, tU2);
    int tU1 = B * 4096 * 256;
    upsample_n_kernel<<<DIVUP(tU1, 256), 256, 0, stream>>>(ws + off_R1, ws + off_up1,
                                                           256, 256, 0.0625f, tU1);
  }

  unsigned long long* pk = (unsigned long long*)(ws + off_pk);
  init_packed_kernel<<<DIVUP(B * 4096, 256), 256, 0, stream>>>(pk, B * 4096);

  // fused R3 GEMM + bicubic add + max/argmax  (128x128 tiles, 8x8 microtile)
  {
    dim3 g(4096 / 128, 4096 / 128, B);
    gemm128_fused_kernel<<<g, 256, 0, stream>>>(ws + off_r3n, ws + off_l3n,
                                                4096, 4096, 576,
                                                ws + off_up2, ws + off_up1, pk);
  }

  int* argp = (int*)(ws + off_arg);
  finalize_kernel<<<DIVUP(B * 4096, 256), 256, 0, stream>>>(pk, out, argp, B * 4096);

  // transfer: fold(gather(unfold(ref_lvX)))/9
  float* T3 = out + 8192;
  float* T2 = T3 + (size_t)B * 256 * 64 * 64;
  float* T1 = T2 + (size_t)B * 128 * 128 * 128;
  {
    int tt = B * 256 * 64 * 64;
    fold_gather_kernel<3, 1, 1><<<DIVUP(tt, 256), 256, 0, stream>>>(ref3, argp, T3, 256, 64, 64, tt);
  }
  {
    int tt = B * 128 * 128 * 128;
    fold_gather_kernel<6, 2, 2><<<DIVUP(tt, 256), 256, 0, stream>>>(ref2, argp, T2, 128, 128, 128, tt);
  }
  {
    int tt = B * 64 * 256 * 256;
    fold_gather_kernel<12, 4, 4><<<DIVUP(tt, 256), 256, 0, stream>>>(ref1, argp, T1, 64, 256, 256, tt);
  }
}

// Round 4
// 1284.875 us; speedup vs baseline: 1.2937x; 1.1473x over previous
//
#include <hip/hip_runtime.h>
#include <cstdint>

#define DIVUP(a,b) (((a)+(b)-1)/(b))

typedef __attribute__((ext_vector_type(4))) float f32x4;
typedef __attribute__((ext_vector_type(8))) _Float16 half8;

__device__ __forceinline__ float cubicw(float x) {
  // PyTorch bicubic kernel, a = -0.75
  float ax = fabsf(x);
  float ax2 = ax * ax;
  float ax3 = ax2 * ax;
  if (ax <= 1.0f) return 1.25f * ax3 - 2.25f * ax2 + 1.0f;
  if (ax < 2.0f)  return -0.75f * ax3 + 3.75f * ax2 - 6.0f * ax + 3.0f;
  return 0.0f;
}

// S[b,pix] = sum_c x[b,c,pix]^2
__global__ void sumsq_kernel(const float* __restrict__ x, float* __restrict__ S,
                             int C, int HW, int total) {
  int i = blockIdx.x * blockDim.x + threadIdx.x;
  if (i >= total) return;
  int pix = i % HW, b = i / HW;
  const float* p = x + (size_t)b * C * HW + pix;
  float s = 0.f;
  for (int c = 0; c < C; ++c) { float v = p[(size_t)c * HW]; s += v * v; }
  S[i] = s;
}

// invn[b,p] = 1 / max(sqrt(3x3 zero-padded window sum of S), 1e-12)
__global__ void invnorm_kernel(const float* __restrict__ S, float* __restrict__ invn,
                               int H, int W, int total) {
  int i = blockIdx.x * blockDim.x + threadIdx.x;
  if (i >= total) return;
  int p = i % (H * W), b = i / (H * W);
  int ph = p / W, pw = p % W;
  const float* Sb = S + (size_t)b * H * W;
  float s = 0.f;
  for (int ki = 0; ki < 3; ++ki) {
    int y = ph + ki - 1;
    if (y < 0 || y >= H) continue;
    for (int kj = 0; kj < 3; ++kj) {
      int xx = pw + kj - 1;
      if (xx < 0 || xx >= W) continue;
      s += Sb[y * W + xx];
    }
  }
  float n = fmaxf(sqrtf(s), 1e-12f);
  invn[i] = 1.0f / n;
}

// l-layout descriptors (fp32, D-major) for levels 1/2
__global__ void desc_l_kernel(const float* __restrict__ x, const float* __restrict__ invn,
                              float* __restrict__ out, int C, int H, int W, int total) {
  int i = blockIdx.x * blockDim.x + threadIdx.x;
  if (i >= total) return;
  int HW = H * W, D = C * 9;
  int p = i % HW;
  int d = (i / HW) % D;
  int b = i / (HW * D);
  int c = d / 9, r = d % 9, ki = r / 3, kj = r % 3;
  int ph = p / W, pw = p % W;
  int y = ph + ki - 1, xx = pw + kj - 1;
  float v = 0.f;
  if (y >= 0 && y < H && xx >= 0 && xx < W) v = x[((size_t)(b * C + c) * H + y) * W + xx];
  out[i] = v * invn[b * HW + p];
}

// r-layout descriptors (fp32, N-major) for levels 1/2
__global__ void desc_r_kernel(const float* __restrict__ x, const float* __restrict__ invn,
                              float* __restrict__ out, int C, int H, int W, int total) {
  int i = blockIdx.x * blockDim.x + threadIdx.x;
  if (i >= total) return;
  int HW = H * W, D = C * 9;
  int d = i % D;
  int p = (i / D) % HW;
  int b = i / (D * HW);
  int c = d / 9, r = d % 9, ki = r / 3, kj = r % 3;
  int ph = p / W, pw = p % W;
  int y = ph + ki - 1, xx = pw + kj - 1;
  float v = 0.f;
  if (y >= 0 && y < H && xx >= 0 && xx < W) v = x[((size_t)(b * C + c) * H + y) * W + xx];
  out[i] = v * invn[b * HW + p];
}

// Level-3 split-f16 descriptors, pixel-major [B][4096][576]:
// hi = f16(v), lo = f16((v-hi)*4096)  (scaled to stay f16-normal)
__global__ void desc_split_kernel(const float* __restrict__ x, const float* __restrict__ invn,
                                  _Float16* __restrict__ hi, _Float16* __restrict__ lo,
                                  int C, int H, int W, int total) {
  int i = blockIdx.x * blockDim.x + threadIdx.x;
  if (i >= total) return;
  int c = i % C;
  int p = (i / C) % (H * W);
  int b = i / (C * H * W);
  int ph = p / W, pw = p % W;
  float s = invn[b * H * W + p];
  size_t obase = ((size_t)b * H * W + p) * (size_t)(C * 9) + (size_t)c * 9;
  const float* xb = x + (size_t)(b * C + c) * H * W;
#pragma unroll
  for (int r = 0; r < 9; ++r) {
    int y = ph + r / 3 - 1, xx = pw + r % 3 - 1;
    float v = 0.f;
    if (y >= 0 && y < H && xx >= 0 && xx < W) v = xb[y * W + xx] * s;
    _Float16 h = (_Float16)v;
    float hf = (float)h;
    _Float16 l = (_Float16)((v - hf) * 4096.0f);
    hi[obase + r] = h;
    lo[obase + r] = l;
  }
}

// Axis-1 bicubic upsample to 4096 rows
__global__ void upsample_n_kernel(const float* __restrict__ Rin, float* __restrict__ out,
                                  int Nin, int cols, float invscale, int total) {
  int i = blockIdx.x * blockDim.x + threadIdx.x;
  if (i >= total) return;
  int j = i % cols;
  int n = (i / cols) & 4095;
  int b = i / (cols * 4096);
  float src = (n + 0.5f) * invscale - 0.5f;
  float f = floorf(src);
  float tt = src - f;
  int fi = (int)f;
  const float* Rb = Rin + (size_t)b * Nin * cols;
  float s = 0.f;
#pragma unroll
  for (int tp = 0; tp < 4; ++tp) {
    int ii = min(max(fi + tp - 1, 0), Nin - 1);
    s += cubicw(tt - (float)(tp - 1)) * Rb[(size_t)ii * cols + j];
  }
  out[i] = s;
}

__global__ void init_packed_kernel(unsigned long long* __restrict__ p, int n) {
  int i = blockIdx.x * blockDim.x + threadIdx.x;
  if (i < n) p[i] = 0ull;
}

// 64x64-tile fp32 GEMM (4x4 microtile), register-prefetch pipelined. R2/R1.
__global__ __launch_bounds__(256)
void gemm64_kernel(const float* __restrict__ A, const float* __restrict__ B,
                   float* __restrict__ C, int M, int N, int K) {
  int b = blockIdx.z;
  const float* Ab = A + (size_t)b * M * K;
  const float* Bb = B + (size_t)b * K * N;
  __shared__ float As[16][68];
  __shared__ float Bs[16][64];
  int row0 = blockIdx.y * 64;
  int col0 = blockIdx.x * 64;
  int t = threadIdx.x;
  int tx = t & 15, ty = t >> 4;
  float acc[4][4] = {};
  int la_r = t >> 2;
  int la_k = (t & 3) << 2;
  int lb_r = t >> 4;
  int lb_c = (t & 15) << 2;
  const float* Aptr = Ab + (size_t)(row0 + la_r) * K + la_k;
  const float* Bptr = Bb + (size_t)lb_r * N + col0 + lb_c;
  float4 av = *(const float4*)(Aptr);
  float4 bv = *(const float4*)(Bptr);
  for (int k0 = 0; k0 < K; k0 += 16) {
    __syncthreads();
    As[la_k + 0][la_r] = av.x;
    As[la_k + 1][la_r] = av.y;
    As[la_k + 2][la_r] = av.z;
    As[la_k + 3][la_r] = av.w;
    *(float4*)&Bs[lb_r][lb_c] = bv;
    __syncthreads();
    if (k0 + 16 < K) {
      av = *(const float4*)(Aptr + k0 + 16);
      bv = *(const float4*)(Bptr + (size_t)(k0 + 16) * N);
    }
#pragma unroll
    for (int k = 0; k < 16; ++k) {
      float4 a = *(const float4*)&As[k][ty << 2];
      float4 bq = *(const float4*)&Bs[k][tx << 2];
      float av4[4] = {a.x, a.y, a.z, a.w};
      float bv4[4] = {bq.x, bq.y, bq.z, bq.w};
#pragma unroll
      for (int ii = 0; ii < 4; ++ii)
#pragma unroll
        for (int jj = 0; jj < 4; ++jj)
          acc[ii][jj] = fmaf(av4[ii], bv4[jj], acc[ii][jj]);
    }
  }
  float* Cb = C + (size_t)b * M * N;
#pragma unroll
  for (int ii = 0; ii < 4; ++ii) {
    float4 v = make_float4(acc[ii][0], acc[ii][1], acc[ii][2], acc[ii][3]);
    *(float4*)&Cb[(size_t)(row0 + (ty << 2) + ii) * N + col0 + (tx << 2)] = v;
  }
}

// MFMA split-f16 GEMM, 128x128 workgroup tile, wave=64x64 (4x4 of 16x16x32),
// fused bicubic-tap add + /3 + packed max/argmax over the ref axis (rows).
// R[n,m] = sum_d A[n][d]*B[m][d]  with A=r3 rows, B=l3 rows (both [4096][576]).
__global__ __launch_bounds__(256)
void mfma_fused_kernel(const _Float16* __restrict__ Ahi, const _Float16* __restrict__ Alo,
                       const _Float16* __restrict__ Bhi, const _Float16* __restrict__ Blo,
                       const float* __restrict__ up2, const float* __restrict__ up1,
                       unsigned long long* __restrict__ packed) {
  const int K = 576;
  int b = blockIdx.z;
  int row0 = blockIdx.y * 128;   // ref axis (n) — argmax axis
  int col0 = blockIdx.x * 128;   // lr axis (m) — output positions
  int t = threadIdx.x;
  int lane = t & 63, wave = t >> 6;
  int wy = wave & 1, wx = wave >> 1;
  int quad = lane >> 4, lm = lane & 15;

  // LDS tiles: [128 rows][32 k + 8 pad] halves = 80 B row stride (16B-aligned)
  __shared__ _Float16 AsH[128 * 40];
  __shared__ _Float16 AsL[128 * 40];
  __shared__ _Float16 BsH[128 * 40];
  __shared__ _Float16 BsL[128 * 40];

  // staging: thread covers row = t&127, 32-byte chunk scu = t>>7 (16 halves)
  int srow = t & 127, scu = t >> 7;
  size_t aoff = ((size_t)b * 4096 + row0 + srow) * (size_t)K + (size_t)scu * 16;
  size_t boff = ((size_t)b * 4096 + col0 + srow) * (size_t)K + (size_t)scu * 16;
  const _Float16* pAH = Ahi + aoff;
  const _Float16* pAL = Alo + aoff;
  const _Float16* pBH = Bhi + boff;
  const _Float16* pBL = Blo + boff;
  int ldsw = srow * 40 + scu * 16;

  f32x4 S1[4][4] = {};
  f32x4 S2[4][4] = {};

  half8 vah0 = *(const half8*)(pAH);
  half8 vah1 = *(const half8*)(pAH + 8);
  half8 val0 = *(const half8*)(pAL);
  half8 val1 = *(const half8*)(pAL + 8);
  half8 vbh0 = *(const half8*)(pBH);
  half8 vbh1 = *(const half8*)(pBH + 8);
  half8 vbl0 = *(const half8*)(pBL);
  half8 vbl1 = *(const half8*)(pBL + 8);

  for (int k0 = 0; k0 < K; k0 += 32) {
    __syncthreads();
    *(half8*)&AsH[ldsw] = vah0;  *(half8*)&AsH[ldsw + 8] = vah1;
    *(half8*)&AsL[ldsw] = val0;  *(half8*)&AsL[ldsw + 8] = val1;
    *(half8*)&BsH[ldsw] = vbh0;  *(half8*)&BsH[ldsw + 8] = vbh1;
    *(half8*)&BsL[ldsw] = vbl0;  *(half8*)&BsL[ldsw + 8] = vbl1;
    __syncthreads();
    if (k0 + 32 < K) {
      vah0 = *(const half8*)(pAH + k0 + 32);
      vah1 = *(const half8*)(pAH + k0 + 40);
      val0 = *(const half8*)(pAL + k0 + 32);
      val1 = *(const half8*)(pAL + k0 + 40);
      vbh0 = *(const half8*)(pBH + k0 + 32);
      vbh1 = *(const half8*)(pBH + k0 + 40);
      vbl0 = *(const half8*)(pBL + k0 + 32);
      vbl1 = *(const half8*)(pBL + k0 + 40);
    }
    half8 aH[4], aL[4], bH[4], bL[4];
#pragma unroll
    for (int i = 0; i < 4; ++i) {
      int ra = (wy * 64 + i * 16 + lm) * 40 + quad * 8;
      aH[i] = *(const half8*)&AsH[ra];
      aL[i] = *(const half8*)&AsL[ra];
      int rb = (wx * 64 + i * 16 + lm) * 40 + quad * 8;
      bH[i] = *(const half8*)&BsH[rb];
      bL[i] = *(const half8*)&BsL[rb];
    }
#pragma unroll
    for (int i = 0; i < 4; ++i)
#pragma unroll
      for (int j = 0; j < 4; ++j) {
        S1[i][j] = __builtin_amdgcn_mfma_f32_16x16x32_f16(aH[i], bH[j], S1[i][j], 0, 0, 0);
        S2[i][j] = __builtin_amdgcn_mfma_f32_16x16x32_f16(aH[i], bL[j], S2[i][j], 0, 0, 0);
        S2[i][j] = __builtin_amdgcn_mfma_f32_16x16x32_f16(aL[i], bH[j], S2[i][j], 0, 0, 0);
      }
  }

  // ---- fused epilogue: v = S1 + S2*2^-12; add bicubic taps; /3; max/argmax ----
  const float inv4096 = 1.0f / 4096.0f;
  const float* u2b = up2 + (size_t)b * 4096 * 1024;
  const float* u1b = up1 + (size_t)b * 4096 * 256;
#pragma unroll
  for (int j = 0; j < 4; ++j) {
    int gm = col0 + wx * 64 + j * 16 + lm;
    float src2 = (gm + 0.5f) * 0.25f - 0.5f;
    float f2 = floorf(src2); float t2 = src2 - f2; int i2 = (int)f2;
    int idx2[4]; float w2[4];
#pragma unroll
    for (int tp = 0; tp < 4; ++tp) {
      idx2[tp] = min(max(i2 + tp - 1, 0), 1023);
      w2[tp] = cubicw(t2 - (float)(tp - 1));
    }
    float src1 = (gm + 0.5f) * 0.0625f - 0.5f;
    float f1 = floorf(src1); float t1 = src1 - f1; int i1 = (int)f1;
    int idx1[4]; float w1[4];
#pragma unroll
    for (int tp = 0; tp < 4; ++tp) {
      idx1[tp] = min(max(i1 + tp - 1, 0), 255);
      w1[tp] = cubicw(t1 - (float)(tp - 1));
    }
    unsigned long long best = 0ull;
#pragma unroll
    for (int i = 0; i < 4; ++i) {
#pragma unroll
      for (int r = 0; r < 4; ++r) {
        int gn = row0 + wy * 64 + i * 16 + quad * 4 + r;
        float v = S1[i][j][r] + S2[i][j][r] * inv4096;
        const float* r2row = u2b + (size_t)gn * 1024;
        const float* r1row = u1b + (size_t)gn * 256;
        v += w2[0] * r2row[idx2[0]] + w2[1] * r2row[idx2[1]]
           + w2[2] * r2row[idx2[2]] + w2[3] * r2row[idx2[3]];
        v += w1[0] * r1row[idx1[0]] + w1[1] * r1row[idx1[1]]
           + w1[2] * r1row[idx1[2]] + w1[3] * r1row[idx1[3]];
        v *= (1.0f / 3.0f);
        unsigned int fb = __float_as_uint(v);
        unsigned int key = (fb & 0x80000000u) ? ~fb : (fb | 0x80000000u);
        unsigned long long pk = ((unsigned long long)key << 32)
                              | (unsigned long long)(0xFFFFFFFFu - (unsigned)gn);
        best = best > pk ? best : pk;
      }
    }
    // combine the 4 quads (same column gm, different row groups)
    unsigned long long o;
    o = __shfl_xor(best, 16); best = best > o ? best : o;
    o = __shfl_xor(best, 32); best = best > o ? best : o;
    if (lane < 16) atomicMax(&packed[(size_t)b * 4096 + gm], best);
  }
}

__global__ void finalize_kernel(const unsigned long long* __restrict__ packed,
                                float* __restrict__ s3_out, int* __restrict__ arg, int total) {
  int i = blockIdx.x * blockDim.x + threadIdx.x;
  if (i >= total) return;
  unsigned long long pk = packed[i];
  unsigned int key = (unsigned int)(pk >> 32);
  unsigned int fb = (key & 0x80000000u) ? (key ^ 0x80000000u) : ~key;
  s3_out[i] = __uint_as_float(fb);
  arg[i] = (int)(0xFFFFFFFFu - (unsigned int)(pk & 0xFFFFFFFFull));
}

// fold(gather(unfold(ref, KK,PP,SS), arg)) / 9 — pure gather, <=9 taps/output.
template<int KK, int SS, int PP>
__global__ void fold_gather_kernel(const float* __restrict__ ref, const int* __restrict__ arg,
                                   float* __restrict__ out, int C, int H, int W, int total) {
  int i = blockIdx.x * blockDim.x + threadIdx.x;
  if (i >= total) return;
  int w = i % W;
  int h = (i / W) % H;
  int c = (i / (W * H)) % C;
  int b = i / (W * H * C);
  int y = h + PP, x = w + PP;
  int ho_lo = (y - KK + 1) > 0 ? (y - KK + 1 + SS - 1) / SS : 0;
  int ho_hi = min(63, y / SS);
  int wo_lo = (x - KK + 1) > 0 ? (x - KK + 1 + SS - 1) / SS : 0;
  int wo_hi = min(63, x / SS);
  const int* argb = arg + b * 4096;
  const float* refb = ref + (size_t)(b * C + c) * H * W;
  float acc = 0.f;
  for (int ho = ho_lo; ho <= ho_hi; ++ho) {
    int ki = y - SS * ho;
    for (int wo = wo_lo; wo <= wo_hi; ++wo) {
      int kj = x - SS * wo;
      int q = argb[(ho << 6) + wo];
      int qh = q >> 6, qw = q & 63;
      int ry = SS * qh + ki - PP;
      int rx = SS * qw + kj - PP;
      if (ry >= 0 && ry < H && rx >= 0 && rx < W) acc += refb[ry * W + rx];
    }
  }
  out[i] = acc * (1.0f / 9.0f);
}

extern "C" void kernel_launch(void* const* d_in, const int* in_sizes, int n_in,
                              void* d_out, int out_size, void* d_ws, size_t ws_size,
                              hipStream_t stream) {
  const float* lrsr1 = (const float*)d_in[0];
  const float* lrsr2 = (const float*)d_in[1];
  const float* lrsr3 = (const float*)d_in[2];
  const float* refsr1 = (const float*)d_in[3];
  const float* refsr2 = (const float*)d_in[4];
  const float* refsr3 = (const float*)d_in[5];
  const float* ref1 = (const float*)d_in[6];
  const float* ref2 = (const float*)d_in[7];
  const float* ref3 = (const float*)d_in[8];
  float* out = (float*)d_out;
  float* ws = (float*)d_ws;

  const int B = 2;
  // level-3 f16 planes occupy the old r3n/l3n fp32 region exactly:
  // 4 planes x [2][4096][576] halves = 9,437,184 floats
  size_t off_planes = 0;
  size_t off_r2n = off_planes + (size_t)B * 4096 * 576 * 2; // floats (= 4 half-planes)
  size_t off_l2n = off_r2n + (size_t)B * 1024 * 1152;   // [2,1152,1024]
  size_t off_r1n = off_l2n + (size_t)B * 1152 * 1024;   // [2,256,2304]
  size_t off_l1n = off_r1n + (size_t)B * 256 * 2304;    // [2,2304,256]
  size_t off_R2  = off_l1n + (size_t)B * 2304 * 256;    // [2,1024,1024]
  size_t off_R1  = off_R2  + (size_t)B * 1024 * 1024;   // [2,256,256]
  size_t off_up2 = off_R1  + (size_t)B * 256 * 256;     // [2,4096,1024]
  size_t off_up1 = off_up2 + (size_t)B * 4096 * 1024;   // [2,4096,256]
  size_t off_S   = off_up1 + (size_t)B * 4096 * 256;    // [2,4096]
  size_t off_invn= off_S   + (size_t)B * 4096;          // [2,4096]
  size_t off_pk  = off_invn+ (size_t)B * 4096;          // [2,4096] u64
  size_t off_arg = off_pk  + (size_t)B * 4096 * 2;      // [2,4096] int

  const size_t PLANE = (size_t)B * 4096 * 576;          // halves per plane
  _Float16* r3hi = (_Float16*)(ws + off_planes);
  _Float16* r3lo = r3hi + PLANE;
  _Float16* l3hi = r3lo + PLANE;
  _Float16* l3lo = l3hi + PLANE;

  auto run_desc32 = [&](const float* x, int C, int H, int W, float* outbuf, bool r_layout) {
    int HW = H * W;
    int tS = B * HW;
    sumsq_kernel<<<DIVUP(tS, 256), 256, 0, stream>>>(x, ws + off_S, C, HW, tS);
    invnorm_kernel<<<DIVUP(tS, 256), 256, 0, stream>>>(ws + off_S, ws + off_invn, H, W, tS);
    int tD = B * C * 9 * HW;
    if (r_layout)
      desc_r_kernel<<<DIVUP(tD, 256), 256, 0, stream>>>(x, ws + off_invn, outbuf, C, H, W, tD);
    else
      desc_l_kernel<<<DIVUP(tD, 256), 256, 0, stream>>>(x, ws + off_invn, outbuf, C, H, W, tD);
  };
  auto run_desc_split = [&](const float* x, _Float16* hi, _Float16* lo) {
    int C = 64, H = 64, W = 64, HW = H * W;
    int tS = B * HW;
    sumsq_kernel<<<DIVUP(tS, 256), 256, 0, stream>>>(x, ws + off_S, C, HW, tS);
    invnorm_kernel<<<DIVUP(tS, 256), 256, 0, stream>>>(ws + off_S, ws + off_invn, H, W, tS);
    int tD = B * C * HW;
    desc_split_kernel<<<DIVUP(tD, 256), 256, 0, stream>>>(x, ws + off_invn, hi, lo, C, H, W, tD);
  };

  // level 3 split-f16 descriptors (both pixel-major [4096][576])
  run_desc_split(refsr3, r3hi, r3lo);
  run_desc_split(lrsr3, l3hi, l3lo);
  // levels 1/2 fp32 descriptors
  run_desc32(lrsr2, 128, 32, 32, ws + off_l2n, false);
  run_desc32(refsr2, 128, 32, 32, ws + off_r2n, true);
  run_desc32(lrsr1, 256, 16, 16, ws + off_l1n, false);
  run_desc32(refsr1, 256, 16, 16, ws + off_r1n, true);

  // small correlation GEMMs R2, R1 (fp32)
  {
    dim3 g(1024 / 64, 1024 / 64, B);
    gemm64_kernel<<<g, 256, 0, stream>>>(ws + off_r2n, ws + off_l2n, ws + off_R2,
                                         1024, 1024, 1152);
  }
  {
    dim3 g(256 / 64, 256 / 64, B);
    gemm64_kernel<<<g, 256, 0, stream>>>(ws + off_r1n, ws + off_l1n, ws + off_R1,
                                         256, 256, 2304);
  }

  // axis-1 bicubic upsample of R2 (x4) and R1 (x16) to 4096 rows
  {
    int tU2 = B * 4096 * 1024;
    upsample_n_kernel<<<DIVUP(tU2, 256), 256, 0, stream>>>(ws + off_R2, ws + off_up2,
                                                           1024, 1024, 0.25f, tU2);
    int tU1 = B * 4096 * 256;
    upsample_n_kernel<<<DIVUP(tU1, 256), 256, 0, stream>>>(ws + off_R1, ws + off_up1,
                                                           256, 256, 0.0625f, tU1);
  }

  unsigned long long* pk = (unsigned long long*)(ws + off_pk);
  init_packed_kernel<<<DIVUP(B * 4096, 256), 256, 0, stream>>>(pk, B * 4096);

  // fused R3 MFMA GEMM + bicubic add + max/argmax
  {
    dim3 g(4096 / 128, 4096 / 128, B);
    mfma_fused_kernel<<<g, 256, 0, stream>>>(r3hi, r3lo, l3hi, l3lo,
                                             ws + off_up2, ws + off_up1, pk);
  }

  int* argp = (int*)(ws + off_arg);
  finalize_kernel<<<DIVUP(B * 4096, 256), 256, 0, stream>>>(pk, out, argp, B * 4096);

  // transfer: fold(gather(unfold(ref_lvX)))/9
  float* T3 = out + 8192;
  float* T2 = T3 + (size_t)B * 256 * 64 * 64;
  float* T1 = T2 + (size_t)B * 128 * 128 * 128;
  {
    int tt = B * 256 * 64 * 64;
    fold_gather_kernel<3, 1, 1><<<DIVUP(tt, 256), 256, 0, stream>>>(ref3, argp, T3, 256, 64, 64, tt);
  }
  {
    int tt = B * 128 * 128 * 128;
    fold_gather_kernel<6, 2, 2><<<DIVUP(tt, 256), 256, 0, stream>>>(ref2, argp, T2, 128, 128, 128, tt);
  }
  {
    int tt = B * 64 * 256 * 256;
    fold_gather_kernel<12, 4, 4><<<DIVUP(tt, 256), 256, 0, stream>>>(ref1, argp, T1, 64, 256, 256, tt);
  }
}